// Round 15
// baseline (204.333 us; speedup 1.0000x reference)
//
#include <hip/hip_runtime.h>
#include <hip/hip_bf16.h>
#include <stdint.h>

// Problem sizes (compile-time)
static constexpr int BATCH = 32768;
static constexpr int DIN   = 512;
static constexpr int DHID  = 1024;
static constexpr int DOUT  = 2048;

typedef __bf16 bf16x8 __attribute__((ext_vector_type(8)));
typedef float  f32x4  __attribute__((ext_vector_type(4)));

// fp32 -> bf16 round-to-nearest-even
__device__ __forceinline__ unsigned short f2bf(float f) {
    unsigned int u = __float_as_uint(f);
    u += 0x7FFFu + ((u >> 16) & 1u);
    return (unsigned short)(u >> 16);
}

// async global->LDS, 16B per lane. LDS dest = WAVE-uniform base + 16*(lane&63).
__device__ __forceinline__ void gload_lds16(const void* g, void* l) {
    __builtin_amdgcn_global_load_lds((__attribute__((address_space(1))) void*)g,
                                     (__attribute__((address_space(3))) void*)l,
                                     16, 0, 0);
}

// ===========================================================================
// scores = x @ W^T + b' (algebraic fusion, r10; absmax 0.03125 measured)
//   W[o,i] = sum_h w2[o,h] w1[h,i];  b'[o] = dot(b1, w2[o,:]) + b2[o]
// Single stream only (r12: hipEvent*/multi-stream breaks graph capture).
// r15: gemmW hidden under the x-convert in ONE dispatch (blocks 0..255 =
// gemmW, 256..16639 = x cvt) — latency-bound gemmW rides along the HBM-bound
// copy. gemmS = the validated 750 TF async-both plateau kernel (untouched).
// ===========================================================================

// ---------------------------------------------------------------------------
// prepW: weights-only pre-work
//   [0,512)    : w1[1024,512] fp32 -> w1t[512,1024] bf16 (transpose)
//   [512,2560) : w2 row o=blk-512: cvt to bf16 + bp[o]=dot(b1,row)+b2[o]
// ---------------------------------------------------------------------------
__global__ __launch_bounds__(256) void prepW_kernel(
    const float* __restrict__ w1, const float4* __restrict__ w2f,
    const float* __restrict__ b1, const float* __restrict__ b2,
    unsigned short* __restrict__ w1t, ushort4* __restrict__ w2b,
    float* __restrict__ bp) {
    const int blk = blockIdx.x;
    const int t   = threadIdx.x;
    if (blk < 512) {
        __shared__ float tile[32][33];
        const int tileI = blk & 15;   // 16 i-tiles (DIN/32)
        const int tileH = blk >> 4;   // 32 h-tiles (DHID/32)
        const int iBase = tileI * 32, hBase = tileH * 32;
        const int col = t & 31, rowq = t >> 5;
#pragma unroll
        for (int p = 0; p < 4; ++p) {
            const int row = p * 8 + rowq;
            tile[row][col] = w1[(size_t)(hBase + row) * DIN + iBase + col];
        }
        __syncthreads();
#pragma unroll
        for (int p = 0; p < 4; ++p) {
            const int row = p * 8 + rowq;   // i-index within tile
            w1t[(size_t)(iBase + row) * DHID + hBase + col] = f2bf(tile[col][row]);
        }
    } else {
        // one block per w2 row: cvt + fused bgemv
        __shared__ float wsum[4];
        const int o = blk - 512;
        const size_t g = (size_t)o * 256 + t;
        float4 v = w2f[g];
        ushort4 ob;
        ob.x = f2bf(v.x); ob.y = f2bf(v.y); ob.z = f2bf(v.z); ob.w = f2bf(v.w);
        w2b[g] = ob;
        float4 bv = ((const float4*)b1)[t];
        float s = v.x * bv.x + v.y * bv.y + v.z * bv.z + v.w * bv.w;
#pragma unroll
        for (int off = 1; off < 64; off <<= 1) s += __shfl_xor(s, off);
        if ((t & 63) == 0) wsum[t >> 6] = s;
        __syncthreads();
        if (t == 0) bp[o] = wsum[0] + wsum[1] + wsum[2] + wsum[3] + b2[o];
    }
}

// ---------------------------------------------------------------------------
// wx: combined dispatch.
//   blocks [0,256)      : gemmW — W[o,i] = sum_h w2b[o,h] * w1t[i,h]
//                         (64x64 tiles, BK=128; grid decode N = blk&7, M = blk>>3)
//   blocks [256,16640)  : x fp32 -> bf16 (4194304 float4 groups)
// gemmW LDS: 64 rows x 128 bf16 = 16 chunks/row, swizzled
//   slot(row,chunk) = row*16 + (chunk ^ (row&15));
// staging slot s = j*256 + wid*64 + lane -> base sA + j*2048 + wid*512
// (wave-uniform base per r13 lesson); global chKey = (tid&15)^((tid>>4)&15).
// Fragment read ch = (ks*4+q) ^ r.
// ---------------------------------------------------------------------------
__global__ __launch_bounds__(256) void wx_kernel(
    const unsigned short* __restrict__ A,   // w2b [2048,1024]
    const unsigned short* __restrict__ Bw,  // w1t [512,1024]
    unsigned short* __restrict__ W,         // out [2048,512] bf16
    const float4* __restrict__ xf, ushort4* __restrict__ xb) {
    if (blockIdx.x >= 256) {
        const size_t g = (size_t)(blockIdx.x - 256) * 256 + threadIdx.x;  // < 4194304
        float4 v = xf[g];
        ushort4 o;
        o.x = f2bf(v.x); o.y = f2bf(v.y); o.z = f2bf(v.z); o.w = f2bf(v.w);
        xb[g] = o;
        return;
    }
    constexpr int K = DHID;
    __shared__ __align__(16) unsigned short sA[64 * 128];  // 16 KB
    __shared__ __align__(16) unsigned short sB[64 * 128];  // 16 KB

    const int tid  = threadIdx.x;
    const int lane = tid & 63;
    const int wid  = tid >> 6;
    const int wr = wid >> 1, wc = wid & 1;
    const int r = lane & 15, q = lane >> 4;
    const int blockN = (blockIdx.x & 7) * 64;
    const int blockM = (blockIdx.x >> 3) * 64;

    const int chKey = (tid & 15) ^ ((tid >> 4) & 15);
    const size_t aBase = (size_t)(blockM + (tid >> 4)) * K + chKey * 8;
    const size_t bBase = (size_t)(blockN + (tid >> 4)) * K + chKey * 8;

    f32x4 acc[2][2];
#pragma unroll
    for (int mt = 0; mt < 2; ++mt)
#pragma unroll
        for (int nt = 0; nt < 2; ++nt) { f32x4 z = {0.f, 0.f, 0.f, 0.f}; acc[mt][nt] = z; }

    for (int k0 = 0; k0 < K; k0 += 128) {
#pragma unroll
        for (int j = 0; j < 4; ++j) {
            gload_lds16(A  + aBase + (size_t)j * 16 * K + k0, sA + j * 2048 + wid * 512);
            gload_lds16(Bw + bBase + (size_t)j * 16 * K + k0, sB + j * 2048 + wid * 512);
        }
        __syncthreads();
#pragma unroll
        for (int ks = 0; ks < 4; ++ks) {
            const int ch = ((ks << 2) + q) ^ r;
            bf16x8 af[2], bf[2];
#pragma unroll
            for (int mt = 0; mt < 2; ++mt) af[mt] = *(const bf16x8*)&sA[(wr * 32 + mt * 16 + r) * 128 + ch * 8];
#pragma unroll
            for (int nt = 0; nt < 2; ++nt) bf[nt] = *(const bf16x8*)&sB[(wc * 32 + nt * 16 + r) * 128 + ch * 8];
#pragma unroll
            for (int mt = 0; mt < 2; ++mt)
#pragma unroll
                for (int nt = 0; nt < 2; ++nt)
                    acc[mt][nt] = __builtin_amdgcn_mfma_f32_16x16x32_bf16(af[mt], bf[nt], acc[mt][nt], 0, 0, 0);
        }
        __syncthreads();
    }

    // store W bf16 [DOUT, DIN]. C/D: col = lane&15, row = q*4+reg.
#pragma unroll
    for (int mt = 0; mt < 2; ++mt) {
        const int row0 = blockM + wr * 32 + mt * 16 + q * 4;
#pragma unroll
        for (int nt = 0; nt < 2; ++nt) {
            const int col = blockN + wc * 32 + nt * 16 + r;
#pragma unroll
            for (int reg = 0; reg < 4; ++reg)
                W[(size_t)(row0 + reg) * DIN + col] = f2bf(acc[mt][nt][reg]);
        }
    }
}

// ---------------------------------------------------------------------------
// gemmS: scores = xb @ W^T + b', fused row-max. BM=128, BN=128, BK=64, K=512.
// Both-async staging (measured 750 TF). One 4096-block XCD-banded grid.
// ---------------------------------------------------------------------------
__global__ __launch_bounds__(256) void gemmS_kernel(
    const unsigned short* __restrict__ A,   // xb bf16 [BATCH, DIN]
    const unsigned short* __restrict__ Bw,  // W bf16 [DOUT, DIN]
    const float* __restrict__ bp,           // b' [DOUT]
    float* __restrict__ partials) {         // [BATCH, 32]
    constexpr int K = DIN;
    __shared__ __align__(16) unsigned short sA[128 * 64];  // 16 KB
    __shared__ __align__(16) unsigned short sB[128 * 64];  // 16 KB

    const int tid  = threadIdx.x;
    const int lane = tid & 63;
    const int wid  = tid >> 6;
    const int wr = wid >> 1, wc = wid & 1;
    const int r = lane & 15, q = lane >> 4;
    const int sw = r & 7;

    // XCD band: 4096 blocks = 8 xcd x (32 M x 16 N)
    const int g    = blockIdx.x;
    const int xcd  = g & 7;
    const int i    = g >> 3;
    const int nIdx = i & 15;
    const int blockM = (xcd * 32 + (i >> 4)) * 128;
    const int blockN = nIdx * 128;

    const int chKey = (lane & 7) ^ (lane >> 3);
    const size_t aBase = (size_t)(blockM + wid * 32 + (lane >> 3)) * K + chKey * 8;
    const size_t bBase = (size_t)(blockN + wid * 32 + (lane >> 3)) * K + chKey * 8;

    f32x4 acc[4][4];
#pragma unroll
    for (int mt = 0; mt < 4; ++mt)
#pragma unroll
        for (int nt = 0; nt < 4; ++nt) { f32x4 z = {0.f, 0.f, 0.f, 0.f}; acc[mt][nt] = z; }

    for (int k0 = 0; k0 < K; k0 += 64) {
#pragma unroll
        for (int j = 0; j < 4; ++j) {
            gload_lds16(A  + aBase + (size_t)j * 8 * K + k0, sA + wid * 2048 + j * 512);
            gload_lds16(Bw + bBase + (size_t)j * 8 * K + k0, sB + wid * 2048 + j * 512);
        }
        __syncthreads();
#pragma unroll
        for (int ks = 0; ks < 2; ++ks) {
            const int ch = ((ks << 2) + q) ^ sw;
            bf16x8 af[4], bf[4];
#pragma unroll
            for (int mt = 0; mt < 4; ++mt) af[mt] = *(const bf16x8*)&sA[(wr * 64 + mt * 16 + r) * 64 + ch * 8];
#pragma unroll
            for (int nt = 0; nt < 4; ++nt) bf[nt] = *(const bf16x8*)&sB[(wc * 64 + nt * 16 + r) * 64 + ch * 8];
#pragma unroll
            for (int mt = 0; mt < 4; ++mt)
#pragma unroll
                for (int nt = 0; nt < 4; ++nt)
                    acc[mt][nt] = __builtin_amdgcn_mfma_f32_16x16x32_bf16(af[mt], bf[nt], acc[mt][nt], 0, 0, 0);
        }
        __syncthreads();
    }

    // Epilogue: +b', max over the wave's 64 cols, 16-lane reduce, write partial.
    const int colBase = blockN + wc * 64;
    const int rowBase = blockM + wr * 64;
    float bv[4];
#pragma unroll
    for (int nt = 0; nt < 4; ++nt) bv[nt] = bp[colBase + nt * 16 + r];

    float mx[4][4];
#pragma unroll
    for (int mt = 0; mt < 4; ++mt)
#pragma unroll
        for (int reg = 0; reg < 4; ++reg) {
            float v = acc[mt][0][reg] + bv[0];
            v = fmaxf(v, acc[mt][1][reg] + bv[1]);
            v = fmaxf(v, acc[mt][2][reg] + bv[2]);
            v = fmaxf(v, acc[mt][3][reg] + bv[3]);
            mx[mt][reg] = v;
        }
#pragma unroll
    for (int off = 1; off < 16; off <<= 1)
#pragma unroll
        for (int mt = 0; mt < 4; ++mt)
#pragma unroll
            for (int reg = 0; reg < 4; ++reg)
                mx[mt][reg] = fmaxf(mx[mt][reg], __shfl_xor(mx[mt][reg], off));

    if (r == 0) {
#pragma unroll
        for (int mt = 0; mt < 4; ++mt)
#pragma unroll
            for (int reg = 0; reg < 4; ++reg) {
                const int row = rowBase + mt * 16 + q * 4 + reg;
                partials[(size_t)row * 32 + nIdx * 2 + wc] = mx[mt][reg];
            }
    }
}

// ---------------------------------------------------------------------------
// reduce: 32 partials per row -> final max
// ---------------------------------------------------------------------------
__global__ __launch_bounds__(256) void reduce_kernel(
    const float4* __restrict__ partials, float* __restrict__ out) {
    const int row = blockIdx.x * blockDim.x + threadIdx.x;
    const float4* p = partials + (size_t)row * 8;
    float m = -INFINITY;
#pragma unroll
    for (int i = 0; i < 8; ++i) {
        float4 v = p[i];
        m = fmaxf(m, fmaxf(fmaxf(v.x, v.y), fmaxf(v.z, v.w)));
    }
    out[row] = m;
}

// ---------------------------------------------------------------------------
extern "C" void kernel_launch(void* const* d_in, const int* in_sizes, int n_in,
                              void* d_out, int out_size, void* d_ws, size_t ws_size,
                              hipStream_t stream) {
    const float* x   = (const float*)d_in[0];
    const float* l1w = (const float*)d_in[1];
    const float* l1b = (const float*)d_in[2];
    const float* w2  = (const float*)d_in[3];
    const float* b2  = (const float*)d_in[4];
    float* out = (float*)d_out;

    char* ws = (char*)d_ws;
    unsigned short* w1t = (unsigned short*)(ws);                 //  1 MB  w1^T bf16 [512,1024]
    unsigned short* w2b = (unsigned short*)(ws + 1048576);       //  4 MB  w2 bf16 [2048,1024]
    unsigned short* Wb  = (unsigned short*)(ws + 5242880);       //  2 MB  W bf16 [2048,512]
    float* bp           = (float*)(ws + 7340032);                //  8 KB  b' fp32 [2048]
    unsigned short* xb  = (unsigned short*)(ws + 7348224);       // 32 MB  x bf16 [32768,512]
    float* partials     = (float*)(ws + 40902656);               //  4 MB  [BATCH,32]

    // 1) weights pre-work: w1 transpose + w2 cvt(+fused bgemv)
    prepW_kernel<<<2560, 256, 0, stream>>>(
        l1w, (const float4*)w2, l1b, b2, w1t, (ushort4*)w2b, bp);

    // 2) combined: gemmW (256 blocks) hidden under x cvt (16384 blocks)
    wx_kernel<<<16640, 256, 0, stream>>>(
        w2b, w1t, Wb, (const float4*)x, (ushort4*)xb);

    // 3) scores = xb @ W^T + b', fused row-max (one 4096-block dispatch)
    gemmS_kernel<<<4096, 256, 0, stream>>>(xb, Wb, bp, partials);

    // 4) final max over 32 partials per row
    reduce_kernel<<<BATCH / 256, 256, 0, stream>>>((const float4*)partials, out);
}

// Round 17
// 201.352 us; speedup vs baseline: 1.0148x; 1.0148x over previous
//
#include <hip/hip_runtime.h>
#include <hip/hip_bf16.h>
#include <stdint.h>

// Problem sizes (compile-time)
static constexpr int BATCH = 32768;
static constexpr int DIN   = 512;
static constexpr int DHID  = 1024;
static constexpr int DOUT  = 2048;

typedef __bf16 bf16x8 __attribute__((ext_vector_type(8)));
typedef float  f32x4  __attribute__((ext_vector_type(4)));

// fp32 -> bf16 round-to-nearest-even
__device__ __forceinline__ unsigned short f2bf(float f) {
    unsigned int u = __float_as_uint(f);
    u += 0x7FFFu + ((u >> 16) & 1u);
    return (unsigned short)(u >> 16);
}

// async global->LDS, 16B per lane. LDS dest = WAVE-uniform base + 16*(lane&63).
__device__ __forceinline__ void gload_lds16(const void* g, void* l) {
    __builtin_amdgcn_global_load_lds((__attribute__((address_space(1))) void*)g,
                                     (__attribute__((address_space(3))) void*)l,
                                     16, 0, 0);
}

// ===========================================================================
// FINAL (r17 = r14 verbatim, the measured-best configuration: 201.2 us).
// scores = x @ W^T + b' (algebraic fusion):
//   W[o,i] = sum_h w2[o,h] w1[h,i];  b'[o] = dot(b1, w2[o,:]) + b2[o]
// — cuts main-GEMM FLOPs 171.8 -> 68.7 GF and kills the 64 MB h round-trip.
// Session-verified design rules baked in:
//  * B operand through LDS always (r7: direct fragment loads = 16 scattered
//    64B segments/instr, 2x regression).
//  * Both operands staged via async global_load_lds (r9: 751 vs 374 TF for
//    inline-convert staging).
//  * XOR-swizzled LDS tiles: slot(row,chunk)=row*8+(chunk^(row&7)) -> 0 bank
//    conflicts measured (r5+).
//  * XCD-banded grid: all N-tiles of an M-band on one XCD -> FETCH at ideal
//    (24.7 MB vs 264 MB M-scattered, r8->r9).
//  * Single stream, no hipEvent* (r12: breaks graph capture); wave-uniform
//    LDS base per global_load_lds issue (r13 race).
//  * gemmS sits at the ~750 TF source-level plateau: 7 structural variants
//    (16x16/32x32, BK32/64, BM256, grid orders, direct-B, inline-cvt,
//    producer-consumer flags r16) all fail to beat the 2-barrier structure;
//    per corpus m99-m141 the path beyond is hand-asm vmcnt pipelining.
// ===========================================================================

// ---------------------------------------------------------------------------
// prep: one dispatch, region-decoded by blockIdx.x
//   [0,512)        : w1[1024,512] fp32 -> w1t[512,1024] bf16 (transpose)
//   [512,2560)     : w2 row o=blk-512: cvt to bf16 + bp[o]=dot(b1,row)+b2[o]
//   [2560,18944)   : x fp32 -> bf16  (4194304 float4 groups)
// ---------------------------------------------------------------------------
__global__ __launch_bounds__(256) void prep_kernel(
    const float* __restrict__ w1, const float4* __restrict__ w2f,
    const float4* __restrict__ xf, const float* __restrict__ b1,
    const float* __restrict__ b2,
    unsigned short* __restrict__ w1t, ushort4* __restrict__ w2b,
    ushort4* __restrict__ xb, float* __restrict__ bp) {
    const int blk = blockIdx.x;
    const int t   = threadIdx.x;
    if (blk < 512) {
        // w1 transpose -> bf16
        __shared__ float tile[32][33];
        const int tileI = blk & 15;   // 16 i-tiles (DIN/32)
        const int tileH = blk >> 4;   // 32 h-tiles (DHID/32)
        const int iBase = tileI * 32, hBase = tileH * 32;
        const int col = t & 31, rowq = t >> 5;
#pragma unroll
        for (int p = 0; p < 4; ++p) {
            const int row = p * 8 + rowq;
            tile[row][col] = w1[(size_t)(hBase + row) * DIN + iBase + col];
        }
        __syncthreads();
#pragma unroll
        for (int p = 0; p < 4; ++p) {
            const int row = p * 8 + rowq;   // i-index within tile
            w1t[(size_t)(iBase + row) * DHID + hBase + col] = f2bf(tile[col][row]);
        }
    } else if (blk < 2560) {
        // one block per w2 row: cvt + fused bgemv
        __shared__ float wsum[4];
        const int o = blk - 512;
        const size_t g = (size_t)o * 256 + t;
        float4 v = w2f[g];
        ushort4 ob;
        ob.x = f2bf(v.x); ob.y = f2bf(v.y); ob.z = f2bf(v.z); ob.w = f2bf(v.w);
        w2b[g] = ob;
        float4 bv = ((const float4*)b1)[t];
        float s = v.x * bv.x + v.y * bv.y + v.z * bv.z + v.w * bv.w;
#pragma unroll
        for (int off = 1; off < 64; off <<= 1) s += __shfl_xor(s, off);
        if ((t & 63) == 0) wsum[t >> 6] = s;
        __syncthreads();
        if (t == 0) bp[o] = wsum[0] + wsum[1] + wsum[2] + wsum[3] + b2[o];
    } else {
        const size_t g = (size_t)(blk - 2560) * 256 + t;  // < 4194304
        float4 v = xf[g];
        ushort4 o;
        o.x = f2bf(v.x); o.y = f2bf(v.y); o.z = f2bf(v.z); o.w = f2bf(v.w);
        xb[g] = o;
    }
}

// ---------------------------------------------------------------------------
// gemmW: W[o,i] = sum_h w2b[o,h] * w1t[i,h]. M=2048, N=512, K=1024.
// 64x64 tiles (256 blocks), BK=128 (8 iters). LDS 64 rows x 128 bf16 =
// 16 chunks/row, swizzled slot(row,chunk) = row*16 + (chunk ^ (row&15)).
// Staging slot s = j*256 + wid*64 + lane -> LDS base sA + j*2048 + wid*512
// (wave-uniform base; r13's bug was omitting wid*512). Global: row = s>>4,
// chunk = (s&15) ^ (row&15) -> chKey = (tid&15)^((tid>>4)&15), issue-indep.
// Fragment read ch = (ks*4+q) ^ r  (fragment row&15 == r).
// ---------------------------------------------------------------------------
__global__ __launch_bounds__(256) void gemmW_kernel(
    const unsigned short* __restrict__ A,   // w2b [2048,1024]
    const unsigned short* __restrict__ Bw,  // w1t [512,1024]
    unsigned short* __restrict__ W) {       // out [2048,512] bf16
    constexpr int K = DHID;
    __shared__ __align__(16) unsigned short sA[64 * 128];  // 16 KB
    __shared__ __align__(16) unsigned short sB[64 * 128];  // 16 KB

    const int tid  = threadIdx.x;
    const int lane = tid & 63;
    const int wid  = tid >> 6;
    const int wr = wid >> 1, wc = wid & 1;
    const int r = lane & 15, q = lane >> 4;
    const int blockN = blockIdx.x * 64;   // 8
    const int blockM = blockIdx.y * 64;   // 32

    const int chKey = (tid & 15) ^ ((tid >> 4) & 15);
    const size_t aBase = (size_t)(blockM + (tid >> 4)) * K + chKey * 8;
    const size_t bBase = (size_t)(blockN + (tid >> 4)) * K + chKey * 8;

    f32x4 acc[2][2];
#pragma unroll
    for (int mt = 0; mt < 2; ++mt)
#pragma unroll
        for (int nt = 0; nt < 2; ++nt) { f32x4 z = {0.f, 0.f, 0.f, 0.f}; acc[mt][nt] = z; }

    for (int k0 = 0; k0 < K; k0 += 128) {
#pragma unroll
        for (int j = 0; j < 4; ++j) {
            gload_lds16(A  + aBase + (size_t)j * 16 * K + k0, sA + j * 2048 + wid * 512);
            gload_lds16(Bw + bBase + (size_t)j * 16 * K + k0, sB + j * 2048 + wid * 512);
        }
        __syncthreads();
#pragma unroll
        for (int ks = 0; ks < 4; ++ks) {
            const int ch = ((ks << 2) + q) ^ r;
            bf16x8 af[2], bf[2];
#pragma unroll
            for (int mt = 0; mt < 2; ++mt) af[mt] = *(const bf16x8*)&sA[(wr * 32 + mt * 16 + r) * 128 + ch * 8];
#pragma unroll
            for (int nt = 0; nt < 2; ++nt) bf[nt] = *(const bf16x8*)&sB[(wc * 32 + nt * 16 + r) * 128 + ch * 8];
#pragma unroll
            for (int mt = 0; mt < 2; ++mt)
#pragma unroll
                for (int nt = 0; nt < 2; ++nt)
                    acc[mt][nt] = __builtin_amdgcn_mfma_f32_16x16x32_bf16(af[mt], bf[nt], acc[mt][nt], 0, 0, 0);
        }
        __syncthreads();
    }

    // store W bf16 [DOUT, DIN]. C/D: col = lane&15, row = q*4+reg.
#pragma unroll
    for (int mt = 0; mt < 2; ++mt) {
        const int row0 = blockM + wr * 32 + mt * 16 + q * 4;
#pragma unroll
        for (int nt = 0; nt < 2; ++nt) {
            const int col = blockN + wc * 32 + nt * 16 + r;
#pragma unroll
            for (int reg = 0; reg < 4; ++reg)
                W[(size_t)(row0 + reg) * DIN + col] = f2bf(acc[mt][nt][reg]);
        }
    }
}

// ---------------------------------------------------------------------------
// gemmS: scores = xb @ W^T + b', fused row-max. BM=128, BN=128, BK=64, K=512.
// Both-async staging (measured 750 TF). One 4096-block XCD-banded grid.
// ---------------------------------------------------------------------------
__global__ __launch_bounds__(256) void gemmS_kernel(
    const unsigned short* __restrict__ A,   // xb bf16 [BATCH, DIN]
    const unsigned short* __restrict__ Bw,  // W bf16 [DOUT, DIN]
    const float* __restrict__ bp,           // b' [DOUT]
    float* __restrict__ partials) {         // [BATCH, 32]
    constexpr int K = DIN;
    __shared__ __align__(16) unsigned short sA[128 * 64];  // 16 KB
    __shared__ __align__(16) unsigned short sB[128 * 64];  // 16 KB

    const int tid  = threadIdx.x;
    const int lane = tid & 63;
    const int wid  = tid >> 6;
    const int wr = wid >> 1, wc = wid & 1;
    const int r = lane & 15, q = lane >> 4;
    const int sw = r & 7;

    // XCD band: 4096 blocks = 8 xcd x (32 M x 16 N)
    const int g    = blockIdx.x;
    const int xcd  = g & 7;
    const int i    = g >> 3;
    const int nIdx = i & 15;
    const int blockM = (xcd * 32 + (i >> 4)) * 128;
    const int blockN = nIdx * 128;

    const int chKey = (lane & 7) ^ (lane >> 3);
    const size_t aBase = (size_t)(blockM + wid * 32 + (lane >> 3)) * K + chKey * 8;
    const size_t bBase = (size_t)(blockN + wid * 32 + (lane >> 3)) * K + chKey * 8;

    f32x4 acc[4][4];
#pragma unroll
    for (int mt = 0; mt < 4; ++mt)
#pragma unroll
        for (int nt = 0; nt < 4; ++nt) { f32x4 z = {0.f, 0.f, 0.f, 0.f}; acc[mt][nt] = z; }

    for (int k0 = 0; k0 < K; k0 += 64) {
#pragma unroll
        for (int j = 0; j < 4; ++j) {
            gload_lds16(A  + aBase + (size_t)j * 8 * K + k0, sA + wid * 2048 + j * 512);
            gload_lds16(Bw + bBase + (size_t)j * 8 * K + k0, sB + wid * 2048 + j * 512);
        }
        __syncthreads();
#pragma unroll
        for (int ks = 0; ks < 2; ++ks) {
            const int ch = ((ks << 2) + q) ^ sw;
            bf16x8 af[4], bf[4];
#pragma unroll
            for (int mt = 0; mt < 4; ++mt) af[mt] = *(const bf16x8*)&sA[(wr * 64 + mt * 16 + r) * 64 + ch * 8];
#pragma unroll
            for (int nt = 0; nt < 4; ++nt) bf[nt] = *(const bf16x8*)&sB[(wc * 64 + nt * 16 + r) * 64 + ch * 8];
#pragma unroll
            for (int mt = 0; mt < 4; ++mt)
#pragma unroll
                for (int nt = 0; nt < 4; ++nt)
                    acc[mt][nt] = __builtin_amdgcn_mfma_f32_16x16x32_bf16(af[mt], bf[nt], acc[mt][nt], 0, 0, 0);
        }
        __syncthreads();
    }

    // Epilogue: +b', max over the wave's 64 cols, 16-lane reduce, write partial.
    const int colBase = blockN + wc * 64;
    const int rowBase = blockM + wr * 64;
    float bv[4];
#pragma unroll
    for (int nt = 0; nt < 4; ++nt) bv[nt] = bp[colBase + nt * 16 + r];

    float mx[4][4];
#pragma unroll
    for (int mt = 0; mt < 4; ++mt)
#pragma unroll
        for (int reg = 0; reg < 4; ++reg) {
            float v = acc[mt][0][reg] + bv[0];
            v = fmaxf(v, acc[mt][1][reg] + bv[1]);
            v = fmaxf(v, acc[mt][2][reg] + bv[2]);
            v = fmaxf(v, acc[mt][3][reg] + bv[3]);
            mx[mt][reg] = v;
        }
#pragma unroll
    for (int off = 1; off < 16; off <<= 1)
#pragma unroll
        for (int mt = 0; mt < 4; ++mt)
#pragma unroll
            for (int reg = 0; reg < 4; ++reg)
                mx[mt][reg] = fmaxf(mx[mt][reg], __shfl_xor(mx[mt][reg], off));

    if (r == 0) {
#pragma unroll
        for (int mt = 0; mt < 4; ++mt)
#pragma unroll
            for (int reg = 0; reg < 4; ++reg) {
                const int row = rowBase + mt * 16 + q * 4 + reg;
                partials[(size_t)row * 32 + nIdx * 2 + wc] = mx[mt][reg];
            }
    }
}

// ---------------------------------------------------------------------------
// reduce: 32 partials per row -> final max
// ---------------------------------------------------------------------------
__global__ __launch_bounds__(256) void reduce_kernel(
    const float4* __restrict__ partials, float* __restrict__ out) {
    const int row = blockIdx.x * blockDim.x + threadIdx.x;
    const float4* p = partials + (size_t)row * 8;
    float m = -INFINITY;
#pragma unroll
    for (int i = 0; i < 8; ++i) {
        float4 v = p[i];
        m = fmaxf(m, fmaxf(fmaxf(v.x, v.y), fmaxf(v.z, v.w)));
    }
    out[row] = m;
}

// ---------------------------------------------------------------------------
extern "C" void kernel_launch(void* const* d_in, const int* in_sizes, int n_in,
                              void* d_out, int out_size, void* d_ws, size_t ws_size,
                              hipStream_t stream) {
    const float* x   = (const float*)d_in[0];
    const float* l1w = (const float*)d_in[1];
    const float* l1b = (const float*)d_in[2];
    const float* w2  = (const float*)d_in[3];
    const float* b2  = (const float*)d_in[4];
    float* out = (float*)d_out;

    char* ws = (char*)d_ws;
    unsigned short* w1t = (unsigned short*)(ws);                 //  1 MB  w1^T bf16 [512,1024]
    unsigned short* w2b = (unsigned short*)(ws + 1048576);       //  4 MB  w2 bf16 [2048,1024]
    unsigned short* Wb  = (unsigned short*)(ws + 5242880);       //  2 MB  W bf16 [2048,512]
    float* bp           = (float*)(ws + 7340032);                //  8 KB  b' fp32 [2048]
    unsigned short* xb  = (unsigned short*)(ws + 7348224);       // 32 MB  x bf16 [32768,512]
    float* partials     = (float*)(ws + 40902656);               //  4 MB  [BATCH,32]

    // 1) fused pre-work: w1 transpose + w2 cvt(+bgemv) + x cvt  (single stream)
    prep_kernel<<<18944, 256, 0, stream>>>(
        l1w, (const float4*)w2, (const float4*)x, l1b, b2,
        w1t, (ushort4*)w2b, (ushort4*)xb, bp);

    // 2) W = w2b @ w1t^T  [2048, 512]  (256 blocks, BK=128)
    gemmW_kernel<<<dim3(DIN / 64, DOUT / 64), 256, 0, stream>>>(w2b, w1t, Wb);

    // 3) scores = xb @ W^T + b', fused row-max (one 4096-block dispatch)
    gemmS_kernel<<<4096, 256, 0, stream>>>(xb, Wb, bp, partials);

    // 4) final max over 32 partials per row
    reduce_kernel<<<BATCH / 256, 256, 0, stream>>>((const float4*)partials, out);
}